// Round 2
// baseline (465.949 us; speedup 1.0000x reference)
//
#include <hip/hip_runtime.h>
#include <math.h>

typedef float f32x4 __attribute__((ext_vector_type(4)));

// Problem constants (from reference)
#define N_NODES 100000
#define C_CL 30
#define D_IN 256

// d_out float offsets: (out, mincut, ortho, Z, S) concatenated
#define OUT_MAT 0        // 30*64
#define OUT_MC 1920
#define OUT_OR 1921
#define OUT_Z 1922       // 30*256
#define OUT_S 9602       // N*30

// ws float offsets
#define WS_M 0           // 30*256  (M = S^T x)      [written by k_reduce_b]
#define WS_SS 7680       // 30*30
#define WS_CS 8580       // 30 (colsum S)
#define WS_CUT 8610      // 1  (zeroed by k_prep, atomic from k_edges)
#define WS_H1 8640       // 30*256
#define WS_H2 16320      // 30*256
#define WS_WT4 24000     // 64*32 float4 = 8192 floats (W padded to 32 cols)
#define WS_S8 32256      // u8 S table: 1563*64 rows * 8 dwords = 3.2 MB (L2-resident)
#define WS_Q 1632768     // stage-A partials: 16 * 8640 floats
#define Q_STRIDE 8640
#define WS_SLAB0 1771008 // per-block partial slabs start (floats)

// slab layout (floats, per block)
#define SLAB_SS 7680     // 4 w-partials * 900
#define SLAB_CS 11280    // 30
#define SLAB_STRIDE 11328
#define MAX_R 512

#define NCHUNK64 ((N_NODES + 63) / 64)   // 1563 chunks of 64 nodes

// ---------------------------------------------------------------------------
// prep: build WT4p[k4][c] (c padded to 32, cols 30/31 = 0); zero WS_CUT
__global__ __launch_bounds__(256)
void k_prep(const float* __restrict__ Wa, float* __restrict__ ws) {
  const int b = blockIdx.x, t = threadIdx.x;
  if (b < 8) {
    const int g = b * 256 + t;          // 0..2047 = 64 k4 * 32 c
    const int k4 = g >> 5, c = g & 31;
    float4 v = make_float4(0.f, 0.f, 0.f, 0.f);
    if (c < C_CL) {
      v.x = Wa[(4 * k4 + 0) * C_CL + c];
      v.y = Wa[(4 * k4 + 1) * C_CL + c];
      v.z = Wa[(4 * k4 + 2) * C_CL + c];
      v.w = Wa[(4 * k4 + 3) * C_CL + c];
    }
    reinterpret_cast<float4*>(ws + WS_WT4)[g] = v;
  } else {
    if (t == 0) ws[WS_CUT] = 0.f;
  }
}

// ---------------------------------------------------------------------------
// k_fused: persistent blocks, grid-stride over 64-node chunks.
// Per chunk:
//   1. stage x tile (64 rows x 256 f = 64 KB) into LDS: 16 coalesced
//      global float4 loads into regs (full MLP), then 16 swizzled
//      ds_write_b128 (granule f of row n lands at f ^ (n&7)).
//   2. logits: wave cg computes clusters [8cg,8cg+8) for 64 nodes (lane=node),
//      x from LDS (swizzled read, 2-way max), W via wave-uniform scalar loads.
//      softmax by wave 0.
//   3. outputs: packed fp32 S + u8 fixed-point S (for k_edges).
//   4. M += S^T x, SS += S^T S, colsum — k_M2's register layout, x/S from LDS.
// End: flush per-block slab (reduced by k_reduce_a/b as before).
__global__ __launch_bounds__(256, 2)
void k_fused(const float* __restrict__ x, const float* __restrict__ wt4f,
             const float* __restrict__ ba, float* __restrict__ S_out,
             unsigned* __restrict__ S8, float* __restrict__ slabs,
             const int R) {
  __shared__ float lx[64 * 256];   // 64 KB x tile (also flush scratch)
  __shared__ float lg[64][33];     // logits / S (stride 33: conflict-free)

  const int t = threadIdx.x;
  const int lane = t & 63;
  const int w = t >> 6;                                   // wave 0..3
  const int cg = __builtin_amdgcn_readfirstlane(w);       // wave-uniform
  // M-phase mapping (identical to old k_M2, chunk halved to 64 nodes)
  const int h = t >> 7;            // cluster half: 0 -> c 0..15, 1 -> 16..31
  const int sub = (t >> 6) & 1;    // node half: 32 nodes each
  const int lc = t & 63;           // feature slice (4 floats)
  // SS mapping
  const int i4 = (t >> 3) & 7, j4 = t & 7;

  const float4* __restrict__ wt4 = reinterpret_cast<const float4*>(wt4f);

  float a[16][4];
  #pragma unroll
  for (int j = 0; j < 16; ++j) { a[j][0] = 0.f; a[j][1] = 0.f; a[j][2] = 0.f; a[j][3] = 0.f; }
  float ssq[16];
  #pragma unroll
  for (int j = 0; j < 16; ++j) ssq[j] = 0.f;
  float cs = 0.f;

  const int lsw = (lane & 7) << 2;      // logit-phase swizzle (floats)
  const int lcsh = lc << 2;             // M-phase feature offset (floats)

  for (int chunk = blockIdx.x; chunk < NCHUNK64; chunk += R) {
    const int node0 = chunk * 64;
    const int rows_valid = min(64, N_NODES - node0);
    __syncthreads();   // previous iteration finished reading lx/lg

    // ---- 1. stage x tile: issue all 16 loads, then 16 swizzled writes ----
    {
      float4 v[16];
      #pragma unroll
      for (int it = 0; it < 16; ++it) {
        const int n = (it << 2) + w;                    // row 0..63
        const int nsrc = (n < rows_valid) ? n : 0;      // clamp tail (unused)
        v[it] = *reinterpret_cast<const float4*>(
            x + (size_t)(node0 + nsrc) * 256 + (lane << 2));
      }
      #pragma unroll
      for (int it = 0; it < 16; ++it) {
        const int n = (it << 2) + w;
        *reinterpret_cast<float4*>(
            &lx[n * 256 + ((lane ^ (n & 7)) << 2)]) = v[it];
      }
    }
    __syncthreads();   // lx ready

    // ---- 2. logits: acc over k4, x from LDS (swizzled), W scalar ----
    {
      float acc[8];
      #pragma unroll
      for (int j = 0; j < 8; ++j) acc[j] = 0.f;
      const float* lrow = &lx[lane * 256];
      #pragma unroll 8
      for (int k4 = 0; k4 < 64; ++k4) {
        const f32x4 xv =
            *reinterpret_cast<const f32x4*>(&lrow[(k4 << 2) ^ lsw]);
        #pragma unroll
        for (int j = 0; j < 8; ++j) {
          const float4 wv = wt4[k4 * 32 + cg * 8 + j];   // scalar loads
          acc[j] += xv.x * wv.x + xv.y * wv.y + xv.z * wv.z + xv.w * wv.w;
        }
      }
      #pragma unroll
      for (int j = 0; j < 8; ++j) lg[lane][cg * 8 + j] = acc[j];
    }
    __syncthreads();

    // ---- softmax by wave 0 ----
    if (t < 64) {
      if (t < rows_valid) {
        float v[C_CL];
        float mx = -3.0e38f;
        #pragma unroll
        for (int c = 0; c < C_CL; ++c) {
          v[c] = lg[t][c] + ba[c];
          mx = fmaxf(mx, v[c]);
        }
        float sm = 0.f;
        #pragma unroll
        for (int c = 0; c < C_CL; ++c) { v[c] = __expf(v[c] - mx); sm += v[c]; }
        const float r = 1.f / sm;
        #pragma unroll
        for (int c = 0; c < C_CL; ++c) lg[t][c] = v[c] * r;
      } else {
        #pragma unroll
        for (int c = 0; c < C_CL; ++c) lg[t][c] = 0.f;
      }
      lg[t][30] = 0.f; lg[t][31] = 0.f;
    }
    __syncthreads();

    // ---- 3. outputs ----
    const int gbase = chunk * 1920;
    #pragma unroll
    for (int i = 0; i < 8; ++i) {
      const unsigned idx = i * 256 + t;
      if (idx < 1920u) {
        const unsigned n = idx / 30u, c = idx - 30u * n;
        const int g = gbase + (int)idx;
        if (g < N_NODES * C_CL) S_out[g] = lg[n][c];
      }
    }
    const unsigned sbase = (unsigned)chunk * 512;
    #pragma unroll
    for (int i = 0; i < 2; ++i) {
      const unsigned idx = i * 256 + t;            // 0..511
      const unsigned n = idx >> 3, j = idx & 7;
      const unsigned b0 = (unsigned)(lg[n][j * 4 + 0] * 255.f + 0.5f);
      const unsigned b1 = (unsigned)(lg[n][j * 4 + 1] * 255.f + 0.5f);
      const unsigned b2 = (unsigned)(lg[n][j * 4 + 2] * 255.f + 0.5f);
      const unsigned b3 = (unsigned)(lg[n][j * 4 + 3] * 255.f + 0.5f);
      S8[sbase + idx] = b0 | (b1 << 8) | (b2 << 16) | (b3 << 24);
    }

    // ---- 4. M += S^T x (zeroed S rows make tail garbage harmless) ----
    #pragma unroll 4
    for (int n = 0; n < 32; ++n) {
      const int nn = sub * 32 + n;
      const f32x4 xv = *reinterpret_cast<const f32x4*>(
          &lx[nn * 256 + (lcsh ^ ((nn & 7) << 2))]);
      float sv[16];
      #pragma unroll
      for (int j = 0; j < 16; ++j) sv[j] = lg[nn][h * 16 + j];  // broadcast
      #pragma unroll
      for (int j = 0; j < 16; ++j) {
        a[j][0] += sv[j] * xv.x; a[j][1] += sv[j] * xv.y;
        a[j][2] += sv[j] * xv.z; a[j][3] += sv[j] * xv.w;
      }
    }

    // ---- SS += S^T S ----
    #pragma unroll 4
    for (int n = 0; n < 16; ++n) {
      const int nn = w * 16 + n;
      float av[4], bv[4];
      #pragma unroll
      for (int ii = 0; ii < 4; ++ii) {
        av[ii] = lg[nn][i4 * 4 + ii];
        bv[ii] = lg[nn][j4 * 4 + ii];
      }
      #pragma unroll
      for (int ii = 0; ii < 4; ++ii)
        #pragma unroll
        for (int jj = 0; jj < 4; ++jj) ssq[ii * 4 + jj] += av[ii] * bv[jj];
    }

    // ---- colsum ----
    if (t < C_CL) {
      #pragma unroll 4
      for (int n = 0; n < 64; ++n) cs += lg[n][t];
    }
  }

  // ---- flush to private slab (lx reused as scratch) ----
  float* __restrict__ slab = slabs + (size_t)blockIdx.x * SLAB_STRIDE;
  __syncthreads();
  if (sub == 1) {
    #pragma unroll
    for (int j = 0; j < 16; ++j) {
      const int c = h * 16 + j;
      if (c < C_CL) {
        #pragma unroll
        for (int q = 0; q < 4; ++q) lx[c * 256 + lc * 4 + q] = a[j][q];
      }
    }
  }
  __syncthreads();
  if (sub == 0) {
    #pragma unroll
    for (int j = 0; j < 16; ++j) {
      const int c = h * 16 + j;
      if (c < C_CL) {
        #pragma unroll
        for (int q = 0; q < 4; ++q)
          slab[c * 256 + lc * 4 + q] = a[j][q] + lx[c * 256 + lc * 4 + q];
      }
    }
  }
  #pragma unroll
  for (int ii = 0; ii < 4; ++ii) {
    #pragma unroll
    for (int jj = 0; jj < 4; ++jj) {
      const int gi = i4 * 4 + ii, gj = j4 * 4 + jj;
      if (gi < C_CL && gj < C_CL)
        slab[SLAB_SS + w * 900 + gi * C_CL + gj] = ssq[ii * 4 + jj];
    }
  }
  if (t < C_CL) slab[SLAB_CS + t] = cs;
}

// ---------------------------------------------------------------------------
// Stage A: 34 x 16 blocks; group g sums its ~R/16 slabs with batched loads.
__global__ __launch_bounds__(256)
void k_reduce_a(const float* __restrict__ slabs, const int R,
                float* __restrict__ Q) {
  const int i = blockIdx.x * 256 + threadIdx.x;
  const int g = blockIdx.y;
  if (i >= 8610) return;
  const int per = (R + 15) >> 4;
  const int r0 = g * per;
  const int r1 = min(r0 + per, R);
  size_t off;
  bool is_ss = false;
  if (i < 7680) off = (size_t)i;
  else if (i < 8580) { off = SLAB_SS + (i - 7680); is_ss = true; }
  else off = SLAB_CS + (i - 8580);

  float s = 0.f;
  if (!is_ss) {
    int r = r0;
    for (; r + 8 <= r1; r += 8) {
      const float* p = slabs + (size_t)r * SLAB_STRIDE + off;
      const float v0 = p[0];
      const float v1 = p[1 * SLAB_STRIDE];
      const float v2 = p[2 * SLAB_STRIDE];
      const float v3 = p[3 * SLAB_STRIDE];
      const float v4 = p[4 * SLAB_STRIDE];
      const float v5 = p[5 * SLAB_STRIDE];
      const float v6 = p[6 * SLAB_STRIDE];
      const float v7 = p[7 * SLAB_STRIDE];
      s += ((v0 + v1) + (v2 + v3)) + ((v4 + v5) + (v6 + v7));
    }
    for (; r < r1; ++r) s += slabs[(size_t)r * SLAB_STRIDE + off];
  } else {
    int r = r0;
    for (; r + 2 <= r1; r += 2) {
      const float* p0 = slabs + (size_t)r * SLAB_STRIDE + off;
      const float* p1 = p0 + SLAB_STRIDE;
      s += ((p0[0] + p0[900]) + (p0[1800] + p0[2700]))
         + ((p1[0] + p1[900]) + (p1[1800] + p1[2700]));
    }
    if (r < r1) {
      const float* p = slabs + (size_t)r * SLAB_STRIDE + off;
      s += (p[0] + p[900]) + (p[1800] + p[2700]);
    }
  }
  Q[(size_t)g * Q_STRIDE + i] = s;
}

// Stage B: ws[i] = sum_g Q[g][i], 16 unrolled independent loads.
__global__ __launch_bounds__(256)
void k_reduce_b(const float* __restrict__ Q, float* __restrict__ ws) {
  const int i = blockIdx.x * 256 + threadIdx.x;
  if (i >= 8610) return;
  float s = 0.f;
  #pragma unroll
  for (int g = 0; g < 16; ++g) s += Q[(size_t)g * Q_STRIDE + i];
  ws[i] = s;
}

// ---------------------------------------------------------------------------
// cut = sum_e dot(S[r], S[c]); u8 rows (32 B, table 3.2 MB -> L2-resident).
__device__ __forceinline__ int dd(unsigned a, unsigned b, int acc) {
  acc += (int)((a & 0xffu) * (b & 0xffu));
  acc += (int)(((a >> 8) & 0xffu) * ((b >> 8) & 0xffu));
  acc += (int)(((a >> 16) & 0xffu) * ((b >> 16) & 0xffu));
  acc += (int)((a >> 24) * (b >> 24));
  return acc;
}

__global__ __launch_bounds__(256)
void k_edges(const int* __restrict__ ei, const int E,
             const unsigned* __restrict__ S8, float* __restrict__ ws) {
  const int t = threadIdx.x;
  const int tid = blockIdx.x * 256 + t;
  const int* __restrict__ row = ei;
  const int* __restrict__ col = ei + E;
  float acc = 0.f;
  for (int e = tid; e < E; e += gridDim.x * 256) {
    const int r = row[e], c = col[e];
    const uint4* pr = reinterpret_cast<const uint4*>(S8 + (size_t)r * 8);
    const uint4* pc = reinterpret_cast<const uint4*>(S8 + (size_t)c * 8);
    const uint4 a0 = pr[0], a1 = pr[1];
    const uint4 b0 = pc[0], b1 = pc[1];
    int s = 0;
    s = dd(a0.x, b0.x, s); s = dd(a0.y, b0.y, s);
    s = dd(a0.z, b0.z, s); s = dd(a0.w, b0.w, s);
    s = dd(a1.x, b1.x, s); s = dd(a1.y, b1.y, s);
    s = dd(a1.z, b1.z, s); s = dd(a1.w, b1.w, s);
    acc += (float)s;
  }
  acc *= (1.f / 65025.f);     // (1/255)^2
  #pragma unroll
  for (int m = 1; m < 64; m <<= 1) acc += __shfl_xor(acc, m, 64);
  __shared__ float wsum[4];
  if ((t & 63) == 0) wsum[t >> 6] = acc;
  __syncthreads();
  if (t == 0)
    atomicAdd(&ws[WS_CUT], wsum[0] + wsum[1] + wsum[2] + wsum[3]);
}

// ---------------------------------------------------------------------------
// Z = M @ W_proj + colsum(S) (x) b_proj
__global__ __launch_bounds__(256)
void k_z(const float* __restrict__ ws, const float* __restrict__ Wp,
         const float* __restrict__ bp, float* __restrict__ out) {
  const int r = blockIdx.x, t = threadIdx.x;
  const float* m = ws + WS_M + r * 256;
  float acc = ws[WS_CS + r] * bp[t];
  #pragma unroll 8
  for (int k = 0; k < 256; ++k) acc += m[k] * Wp[(size_t)k * 256 + t];
  out[OUT_Z + r * 256 + t] = acc;
}

// ---------------------------------------------------------------------------
// Shapley layer (mask=ones, n=30): h = relu((in + colsum(in)/30) @ W)
__global__ __launch_bounds__(256)
void k_shlayer(const float* __restrict__ in, const float* __restrict__ W,
               float* __restrict__ outp) {
  __shared__ float sh[256];
  const int r = blockIdx.x, t = threadIdx.x;
  float cs = 0.f;
  #pragma unroll
  for (int i = 0; i < C_CL; ++i) cs += in[i * 256 + t];
  sh[t] = in[r * 256 + t] + (1.f / 30.f) * cs;
  __syncthreads();
  float acc = 0.f;
  #pragma unroll 8
  for (int k = 0; k < 256; ++k) acc += sh[k] * W[(size_t)k * 256 + t];
  outp[r * 256 + t] = fmaxf(acc, 0.f);
}

// ---------------------------------------------------------------------------
// out = h2 @ W_out + b_out ; block 30: mincut + ortho scalars
__global__ __launch_bounds__(64)
void k_out(const float* __restrict__ ws, const float* __restrict__ Wo,
           const float* __restrict__ bo, float* __restrict__ out,
           const float vol) {
  const int r = blockIdx.x, t = threadIdx.x;
  if (r < C_CL) {
    const float* hrow = ws + WS_H2 + r * 256;
    float acc = bo[t];
    #pragma unroll 8
    for (int k = 0; k < 256; ++k) acc += hrow[k] * Wo[k * 64 + t];
    out[OUT_MAT + r * 64 + t] = acc;
  } else {
    float s = 0.f;
    for (int i = t; i < C_CL * C_CL; i += 64) {
      const float d = ws[WS_SS + i] - ((i / C_CL == i % C_CL) ? 1.f : 0.f);
      s += d * d;
    }
    #pragma unroll
    for (int m = 32; m >= 1; m >>= 1) s += __shfl_xor(s, m, 64);
    if (t == 0) {
      out[OUT_OR] = sqrtf(s);
      out[OUT_MC] = -ws[WS_CUT] / (vol + 1e-9f);
    }
  }
}

// ---------------------------------------------------------------------------
extern "C" void kernel_launch(void* const* d_in, const int* in_sizes, int n_in,
                              void* d_out, int out_size, void* d_ws, size_t ws_size,
                              hipStream_t stream) {
  (void)n_in; (void)out_size;
  const float* x  = (const float*)d_in[0];
  const int*   ei = (const int*)d_in[1];
  const float* Wa = (const float*)d_in[2];
  const float* ba = (const float*)d_in[3];
  const float* Wp = (const float*)d_in[4];
  const float* bp = (const float*)d_in[5];
  const float* W1 = (const float*)d_in[6];
  const float* W2 = (const float*)d_in[7];
  const float* Wo = (const float*)d_in[8];
  const float* bo = (const float*)d_in[9];
  float* out = (float*)d_out;
  float* ws  = (float*)d_ws;
  unsigned* S8 = (unsigned*)(ws + WS_S8);
  float* Q = ws + WS_Q;
  float* slabs = ws + WS_SLAB0;
  const int E = in_sizes[1] / 2;

  long avail = (long)(ws_size / 4) - WS_SLAB0;
  int R = (int)(avail / SLAB_STRIDE);
  if (R > MAX_R) R = MAX_R;
  if (R < 1) R = 1;

  k_prep<<<9, 256, 0, stream>>>(Wa, ws);
  k_fused<<<R, 256, 0, stream>>>(x, ws + WS_WT4, ba, out + OUT_S, S8, slabs, R);
  k_reduce_a<<<dim3(34, 16), 256, 0, stream>>>(slabs, R, Q);
  k_reduce_b<<<34, 256, 0, stream>>>(Q, ws);
  k_edges<<<4096, 256, 0, stream>>>(ei, E, S8, ws);
  k_z<<<C_CL, 256, 0, stream>>>(ws, Wp, bp, out);
  k_shlayer<<<C_CL, 256, 0, stream>>>(out + OUT_Z, W1, ws + WS_H1);
  k_shlayer<<<C_CL, 256, 0, stream>>>(ws + WS_H1, W2, ws + WS_H2);
  k_out<<<C_CL + 1, 64, 0, stream>>>(ws, Wo, bo, out, (float)E);
}